// Round 1
// baseline (17539.488 us; speedup 1.0000x reference)
//
#include <hip/hip_runtime.h>
#include <hip/hip_bf16.h>
#include <math.h>

#define N_NODES 190464
#define F_IN 5
#define HEADS 4
#define C_OUT 24
#define NPG 186
#define KW 62
#define OCH 8
#define TOUT 125

// ---------- helpers ----------
__device__ __forceinline__ float lrelu2(float v) { return v > 0.f ? v : 0.2f * v; }

// monotonic float -> uint mapping for atomicMax on floats
__device__ __forceinline__ unsigned fmap(float f) {
    unsigned u = __float_as_uint(f);
    return (u & 0x80000000u) ? ~u : (u | 0x80000000u);
}
__device__ __forceinline__ float funmap(unsigned u) {
    unsigned b = (u & 0x80000000u) ? (u & 0x7fffffffu) : ~u;
    return __uint_as_float(b);
}

// ---------- 1. BN batch statistics ----------
__global__ __launch_bounds__(256) void bn_stats(const float* __restrict__ x,
                                                double* __restrict__ stats) {
    double s[5] = {0, 0, 0, 0, 0}, ss[5] = {0, 0, 0, 0, 0};
    int stride = gridDim.x * blockDim.x;
    for (int n = blockIdx.x * blockDim.x + threadIdx.x; n < N_NODES; n += stride) {
#pragma unroll
        for (int f = 0; f < 5; ++f) {
            float v = x[n * 5 + f];
            s[f] += v;
            ss[f] += (double)v * (double)v;
        }
    }
#pragma unroll
    for (int f = 0; f < 5; ++f) {
        for (int off = 32; off; off >>= 1) {
            s[f] += __shfl_down(s[f], off);
            ss[f] += __shfl_down(ss[f], off);
        }
    }
    if ((threadIdx.x & 63) == 0) {
#pragma unroll
        for (int f = 0; f < 5; ++f) {
            unsafeAtomicAdd(&stats[f], s[f]);
            unsafeAtomicAdd(&stats[5 + f], ss[f]);
        }
    }
}

// ---------- 2. finalize BN to scale/shift ----------
__global__ void bn_finalize(const double* __restrict__ stats,
                            const float* __restrict__ gamma,
                            const float* __restrict__ beta,
                            float* __restrict__ sc) {
    int f = threadIdx.x;
    if (f < 5) {
        double mu = stats[f] / (double)N_NODES;
        double var = stats[5 + f] / (double)N_NODES - mu * mu;
        double rstd = 1.0 / sqrt(var + 1e-5);
        float scale = (float)rstd * gamma[f];
        sc[f] = scale;
        sc[5 + f] = beta[f] - (float)mu * scale;
    }
}

// ---------- 3. per-node linear + attention coefficients ----------
__global__ __launch_bounds__(256) void node_linear(
    const float* __restrict__ x, const float* __restrict__ sc,
    const float* __restrict__ lin_w, const float* __restrict__ att_src,
    const float* __restrict__ att_dst, float* __restrict__ hg,
    float* __restrict__ asg, float* __restrict__ adg) {
    __shared__ float wsm[480];
    __shared__ float asv[96];
    __shared__ float adv[96];
    __shared__ float xt[320];
    __shared__ float scs[10];
    __shared__ float ht[64 * 100];  // stride 100 to break bank conflicts

    int tid = threadIdx.x;
    int n0 = blockIdx.x * 64;
    for (int i = tid; i < 480; i += 256) wsm[i] = lin_w[i];
    if (tid < 96) asv[tid] = att_src[tid];
    else if (tid < 192) adv[tid - 96] = att_dst[tid - 96];
    for (int i = tid; i < 320; i += 256) xt[i] = x[(size_t)n0 * 5 + i];
    if (tid < 10) scs[tid] = sc[tid];
    __syncthreads();

    int nl = tid >> 2, hh = tid & 3;
    float xn[5];
#pragma unroll
    for (int f = 0; f < 5; ++f) xn[f] = xt[nl * 5 + f] * scs[f] + scs[5 + f];
    float av = 0.f, bv = 0.f;
#pragma unroll
    for (int c = 0; c < 24; ++c) {
        int o = hh * 24 + c;
        float acc = 0.f;
#pragma unroll
        for (int f = 0; f < 5; ++f) acc += wsm[o * 5 + f] * xn[f];
        ht[nl * 100 + o] = acc;
        av += acc * asv[o];
        bv += acc * adv[o];
    }
    asg[(size_t)n0 * 4 + tid] = av;
    adg[(size_t)n0 * 4 + tid] = bv;
    __syncthreads();
    for (int i = tid; i < 6144; i += 256)
        hg[(size_t)n0 * 96 + i] = ht[(i / 96) * 100 + (i % 96)];
}

// ---------- 4. segment max over dst ----------
__global__ __launch_bounds__(256) void edge_max(
    const int* __restrict__ ei, const int E, const int total,
    const float* __restrict__ asg, const float* __restrict__ adg,
    unsigned* __restrict__ mbuf) {
    int idx = blockIdx.x * 256 + threadIdx.x;
    if (idx >= total) return;
    int src, dst;
    if (idx < E) { src = ei[idx]; dst = ei[E + idx]; }
    else { src = dst = idx - E; }
    float4 a = ((const float4*)asg)[src];
    float4 b = ((const float4*)adg)[dst];
    unsigned* m = mbuf + (size_t)dst * 4;
    atomicMax(m + 0, fmap(lrelu2(a.x + b.x)));
    atomicMax(m + 1, fmap(lrelu2(a.y + b.y)));
    atomicMax(m + 2, fmap(lrelu2(a.z + b.z)));
    atomicMax(m + 3, fmap(lrelu2(a.w + b.w)));
}

// ---------- 5. edge accumulation: denom += e ; accum += e * h[src] ----------
__global__ __launch_bounds__(256) void edge_accum(
    const int* __restrict__ ei, const int E, const int total,
    const float* __restrict__ asg, const float* __restrict__ adg,
    const unsigned* __restrict__ mbuf, const float* __restrict__ hg,
    float* __restrict__ denom, float* __restrict__ accum) {
    int idx = blockIdx.x * 256 + threadIdx.x;
    if (idx >= total) return;
    int src, dst;
    if (idx < E) { src = ei[idx]; dst = ei[E + idx]; }
    else { src = dst = idx - E; }
    float4 a = ((const float4*)asg)[src];
    float4 b = ((const float4*)adg)[dst];
    uint4 m = ((const uint4*)mbuf)[dst];
    float e0 = expf(lrelu2(a.x + b.x) - funmap(m.x));
    float e1 = expf(lrelu2(a.y + b.y) - funmap(m.y));
    float e2 = expf(lrelu2(a.z + b.z) - funmap(m.z));
    float e3 = expf(lrelu2(a.w + b.w) - funmap(m.w));
    float* dn = denom + (size_t)dst * 4;
    unsafeAtomicAdd(dn + 0, e0);
    unsafeAtomicAdd(dn + 1, e1);
    unsafeAtomicAdd(dn + 2, e2);
    unsafeAtomicAdd(dn + 3, e3);
    const float4* hv = (const float4*)(hg + (size_t)src * 96);
    float* ac = accum + (size_t)dst * 96;
    float ee[4] = {e0, e1, e2, e3};
#pragma unroll
    for (int q = 0; q < 24; ++q) {
        float4 v = hv[q];
        float w = ee[q / 6];
        unsafeAtomicAdd(ac + q * 4 + 0, w * v.x);
        unsafeAtomicAdd(ac + q * 4 + 1, w * v.y);
        unsafeAtomicAdd(ac + q * 4 + 2, w * v.z);
        unsafeAtomicAdd(ac + q * 4 + 3, w * v.w);
    }
}

// ---------- 6. per-node finalize: mean heads + bias + ELU ----------
__global__ __launch_bounds__(256) void node_fin(
    const float* __restrict__ accum, const float* __restrict__ denom,
    const float* __restrict__ bias, float* __restrict__ gat) {
    int n = blockIdx.x * blockDim.x + threadIdx.x;
    if (n >= N_NODES) return;
    float4 d = ((const float4*)denom)[n];
    float i0 = 0.25f / (d.x + 1e-16f);
    float i1 = 0.25f / (d.y + 1e-16f);
    float i2 = 0.25f / (d.z + 1e-16f);
    float i3 = 0.25f / (d.w + 1e-16f);
    const float* ac = accum + (size_t)n * 96;
    float* g = gat + (size_t)n * 24;
#pragma unroll
    for (int c = 0; c < 24; ++c) {
        float s = ac[c] * i0 + ac[24 + c] * i1 + ac[48 + c] * i2 + ac[72 + c] * i3;
        s += bias[c];
        g[c] = s > 0.f ? s : expm1f(s);
    }
}

// ---------- 7. per-graph Conv1d(24->8, k=62) + leaky_relu ----------
__global__ __launch_bounds__(256) void conv_k(
    const float* __restrict__ gat, const float* __restrict__ w,
    const float* __restrict__ b, float* __restrict__ out) {
    __shared__ float it[24][192];
    __shared__ float wsh[OCH * 24 * KW];  // 11904 floats
    int g = blockIdx.x, tid = threadIdx.x;
    // load node features transposed: it[c][p] = gat[g*186+p][c]
    for (int i = tid; i < NPG * 24; i += 256) {
        int p = i / 24, c = i % 24;
        it[c][p] = gat[(size_t)g * (NPG * 24) + i];
    }
    if (tid < 24 * 6) {  // zero pad columns 186..191
        int c = tid / 6;
        it[c][186 + (tid % 6)] = 0.f;
    }
    for (int i = tid; i < OCH * 24 * KW; i += 256) wsh[i] = w[i];
    __syncthreads();

    int o = tid >> 5, tt = tid & 31;
    int t0 = tt * 4;
    float bias = b[o];
    float a0 = bias, a1 = bias, a2 = bias, a3 = bias;
    for (int i = 0; i < 24; ++i) {
        const float* wr = &wsh[(o * 24 + i) * KW];
        const float* ir = &it[i][t0];
        float v0 = ir[0], v1 = ir[1], v2 = ir[2];
#pragma unroll
        for (int k = 0; k < KW; ++k) {
            float v3 = ir[k + 3];
            float wv = wr[k];
            a0 += wv * v0;
            a1 += wv * v1;
            a2 += wv * v2;
            a3 += wv * v3;
            v0 = v1; v1 = v2; v2 = v3;
        }
    }
    a0 = a0 > 0.f ? a0 : 0.01f * a0;
    a1 = a1 > 0.f ? a1 : 0.01f * a1;
    a2 = a2 > 0.f ? a2 : 0.01f * a2;
    a3 = a3 > 0.f ? a3 : 0.01f * a3;
    size_t base = ((size_t)g * OCH + o) * TOUT + t0;
    if (t0 + 0 < TOUT) out[base + 0] = a0;
    if (t0 + 1 < TOUT) out[base + 1] = a1;
    if (t0 + 2 < TOUT) out[base + 2] = a2;
    if (t0 + 3 < TOUT) out[base + 3] = a3;
}

extern "C" void kernel_launch(void* const* d_in, const int* in_sizes, int n_in,
                              void* d_out, int out_size, void* d_ws, size_t ws_size,
                              hipStream_t stream) {
    const float* x        = (const float*)d_in[0];
    const int*   ei       = (const int*)d_in[1];
    // d_in[2] batch: unused (graph id = n / 186)
    const float* bn_gamma = (const float*)d_in[3];
    const float* bn_beta  = (const float*)d_in[4];
    const float* lin_w    = (const float*)d_in[5];
    const float* att_src  = (const float*)d_in[6];
    const float* att_dst  = (const float*)d_in[7];
    const float* gat_bias = (const float*)d_in[8];
    const float* conv_w   = (const float*)d_in[9];
    const float* conv_b   = (const float*)d_in[10];
    float* out = (float*)d_out;
    float* wsf = (float*)d_ws;

    const int N = N_NODES;
    const int E = in_sizes[1] / 2;
    const int total = E + N;

    // ws layout (floats):
    // [0..63]            stats: double sum[5], sumsq[5]; float scale[5]@20, shift[5]@25
    // [64 ..)            accum  N*96
    // then               mbuf   N*4 (uint)
    // then               denom  N*4
    // then               h      N*96   (reused for gat output N*24)
    // then               a_src  N*4
    // then               a_dst  N*4
    size_t offAccum = 64;
    size_t offM     = offAccum + (size_t)N * 96;
    size_t offDenom = offM + (size_t)N * 4;
    size_t offH     = offDenom + (size_t)N * 4;
    size_t offAs    = offH + (size_t)N * 96;
    size_t offAd    = offAs + (size_t)N * 4;

    float*    accum = wsf + offAccum;
    unsigned* mbuf  = (unsigned*)(wsf + offM);
    float*    den   = wsf + offDenom;
    float*    hg    = wsf + offH;
    float*    asg   = wsf + offAs;
    float*    adg   = wsf + offAd;

    // zero stats + accum + mbuf + denom in one contiguous memset
    size_t zeroBytes = (offDenom + (size_t)N * 4) * sizeof(float);
    hipMemsetAsync(d_ws, 0, zeroBytes, stream);

    bn_stats<<<256, 256, 0, stream>>>(x, (double*)wsf);
    bn_finalize<<<1, 64, 0, stream>>>((const double*)wsf, bn_gamma, bn_beta, wsf + 20);
    node_linear<<<N / 64, 256, 0, stream>>>(x, wsf + 20, lin_w, att_src, att_dst,
                                            hg, asg, adg);
    int eb = (total + 255) / 256;
    edge_max<<<eb, 256, 0, stream>>>(ei, E, total, asg, adg, mbuf);
    edge_accum<<<eb, 256, 0, stream>>>(ei, E, total, asg, adg, mbuf, hg, den, accum);
    node_fin<<<(N + 255) / 256, 256, 0, stream>>>(accum, den, gat_bias, hg);
    conv_k<<<N / NPG, 256, 0, stream>>>(hg, conv_w, conv_b, out);
}

// Round 2
// 990.415 us; speedup vs baseline: 17.7092x; 17.7092x over previous
//
#include <hip/hip_runtime.h>
#include <hip/hip_bf16.h>
#include <math.h>

#define N_NODES 190464
#define F_IN 5
#define HEADS 4
#define C_OUT 24
#define NPG 186
#define KW 62
#define OCH 8
#define TOUT 125

// ---------- helpers ----------
__device__ __forceinline__ float lrelu2(float v) { return v > 0.f ? v : 0.2f * v; }

// ---------- 1. BN batch statistics ----------
__global__ __launch_bounds__(256) void bn_stats(const float* __restrict__ x,
                                                double* __restrict__ stats) {
    double s[5] = {0, 0, 0, 0, 0}, ss[5] = {0, 0, 0, 0, 0};
    int stride = gridDim.x * blockDim.x;
    for (int n = blockIdx.x * blockDim.x + threadIdx.x; n < N_NODES; n += stride) {
#pragma unroll
        for (int f = 0; f < 5; ++f) {
            float v = x[n * 5 + f];
            s[f] += v;
            ss[f] += (double)v * (double)v;
        }
    }
#pragma unroll
    for (int f = 0; f < 5; ++f) {
        for (int off = 32; off; off >>= 1) {
            s[f] += __shfl_down(s[f], off);
            ss[f] += __shfl_down(ss[f], off);
        }
    }
    if ((threadIdx.x & 63) == 0) {
#pragma unroll
        for (int f = 0; f < 5; ++f) {
            unsafeAtomicAdd(&stats[f], s[f]);
            unsafeAtomicAdd(&stats[5 + f], ss[f]);
        }
    }
}

// ---------- 2. finalize BN to scale/shift ----------
__global__ void bn_finalize(const double* __restrict__ stats,
                            const float* __restrict__ gamma,
                            const float* __restrict__ beta,
                            float* __restrict__ sc) {
    int f = threadIdx.x;
    if (f < 5) {
        double mu = stats[f] / (double)N_NODES;
        double var = stats[5 + f] / (double)N_NODES - mu * mu;
        double rstd = 1.0 / sqrt(var + 1e-5);
        float scale = (float)rstd * gamma[f];
        sc[f] = scale;
        sc[5 + f] = beta[f] - (float)mu * scale;
    }
}

// ---------- 3. per-node linear + attention coefficients ----------
__global__ __launch_bounds__(256) void node_linear(
    const float* __restrict__ x, const float* __restrict__ sc,
    const float* __restrict__ lin_w, const float* __restrict__ att_src,
    const float* __restrict__ att_dst, float* __restrict__ hg,
    float* __restrict__ asg, float* __restrict__ adg) {
    __shared__ float wsm[480];
    __shared__ float asv[96];
    __shared__ float adv[96];
    __shared__ float xt[320];
    __shared__ float scs[10];
    __shared__ float ht[64 * 100];  // stride 100 to break bank conflicts

    int tid = threadIdx.x;
    int n0 = blockIdx.x * 64;
    for (int i = tid; i < 480; i += 256) wsm[i] = lin_w[i];
    if (tid < 96) asv[tid] = att_src[tid];
    else if (tid < 192) adv[tid - 96] = att_dst[tid - 96];
    for (int i = tid; i < 320; i += 256) xt[i] = x[(size_t)n0 * 5 + i];
    if (tid < 10) scs[tid] = sc[tid];
    __syncthreads();

    int nl = tid >> 2, hh = tid & 3;
    float xn[5];
#pragma unroll
    for (int f = 0; f < 5; ++f) xn[f] = xt[nl * 5 + f] * scs[f] + scs[5 + f];
    float av = 0.f, bv = 0.f;
#pragma unroll
    for (int c = 0; c < 24; ++c) {
        int o = hh * 24 + c;
        float acc = 0.f;
#pragma unroll
        for (int f = 0; f < 5; ++f) acc += wsm[o * 5 + f] * xn[f];
        ht[nl * 100 + o] = acc;
        av += acc * asv[o];
        bv += acc * adv[o];
    }
    asg[(size_t)n0 * 4 + tid] = av;
    adg[(size_t)n0 * 4 + tid] = bv;
    __syncthreads();
    for (int i = tid; i < 6144; i += 256)
        hg[(size_t)n0 * 96 + i] = ht[(i / 96) * 100 + (i % 96)];
}

// ---------- 4. degree count (by dst, incl. self loops) ----------
__global__ __launch_bounds__(256) void deg_count(
    const int* __restrict__ ei, const int E, const int total,
    int* __restrict__ deg) {
    int idx = blockIdx.x * 256 + threadIdx.x;
    if (idx >= total) return;
    int dst = (idx < E) ? ei[E + idx] : (idx - E);
    atomicAdd(&deg[dst], 1);
}

// ---------- 5a. per-block partial sums (1024 elems/block, 186 blocks) ----------
__global__ __launch_bounds__(256) void scan_partial(const int* __restrict__ deg,
                                                    int* __restrict__ psum) {
    __shared__ int red[4];
    int b = blockIdx.x, tid = threadIdx.x;
    int s = 0;
    for (int i = tid; i < 1024; i += 256) s += deg[b * 1024 + i];
    for (int off = 32; off; off >>= 1) s += __shfl_down(s, off);
    if ((tid & 63) == 0) red[tid >> 6] = s;
    __syncthreads();
    if (tid == 0) psum[b] = red[0] + red[1] + red[2] + red[3];
}

// ---------- 5b. tiny sequential exclusive scan of 186 block sums ----------
__global__ void scan_small(int* __restrict__ psum, int* __restrict__ rowptr,
                           const int nblk) {
    if (threadIdx.x == 0 && blockIdx.x == 0) {
        int run = 0;
        for (int i = 0; i < nblk; ++i) {
            int t = psum[i];
            psum[i] = run;
            run += t;
        }
        rowptr[N_NODES] = run;
    }
}

// ---------- 5c. block exclusive scan + write rowptr & cursor ----------
__global__ __launch_bounds__(256) void scan_final(
    const int* __restrict__ deg, const int* __restrict__ psum,
    int* __restrict__ rowptr, int* __restrict__ cursor) {
    __shared__ int ts[256];
    int b = blockIdx.x, tid = threadIdx.x;
    int base = b * 1024 + tid * 4;
    int d0 = deg[base], d1 = deg[base + 1], d2 = deg[base + 2], d3 = deg[base + 3];
    int tsum = d0 + d1 + d2 + d3;
    ts[tid] = tsum;
    __syncthreads();
    for (int off = 1; off < 256; off <<= 1) {
        int v = (tid >= off) ? ts[tid - off] : 0;
        __syncthreads();
        ts[tid] += v;
        __syncthreads();
    }
    int excl = ts[tid] - tsum + psum[b];
    int r0 = excl, r1 = r0 + d0, r2 = r1 + d1, r3 = r2 + d2;
    rowptr[base] = r0; rowptr[base + 1] = r1;
    rowptr[base + 2] = r2; rowptr[base + 3] = r3;
    cursor[base] = r0; cursor[base + 1] = r1;
    cursor[base + 2] = r2; cursor[base + 3] = r3;
}

// ---------- 6. fill edge buckets ----------
__global__ __launch_bounds__(256) void fill_buckets(
    const int* __restrict__ ei, const int E, const int total,
    int* __restrict__ cursor, int* __restrict__ ebuf) {
    int idx = blockIdx.x * 256 + threadIdx.x;
    if (idx >= total) return;
    int src, dst;
    if (idx < E) { src = ei[idx]; dst = ei[E + idx]; }
    else { src = dst = idx - E; }
    int pos = atomicAdd(&cursor[dst], 1);
    ebuf[pos] = src;
}

// ---------- 7. gather GAT: softmax + weighted sum + head mean + ELU ----------
__global__ __launch_bounds__(256) void gat_gather(
    const int* __restrict__ rowptr, const int* __restrict__ ebuf,
    const float* __restrict__ asg, const float* __restrict__ adg,
    const float* __restrict__ hg, const float* __restrict__ bias,
    float* __restrict__ gout) {
    int t = blockIdx.x * 256 + threadIdx.x;
    int n = t >> 2, h = t & 3;
    if (n >= N_NODES) return;
    int beg = rowptr[n], end = rowptr[n + 1];
    float ad = adg[(size_t)n * 4 + h];
    float m = -1e30f;
    for (int i = beg; i < end; ++i) {
        int s = ebuf[i];
        float lg = lrelu2(asg[(size_t)s * 4 + h] + ad);
        m = fmaxf(m, lg);
    }
    float acc[24];
#pragma unroll
    for (int c = 0; c < 24; ++c) acc[c] = 0.f;
    float denom = 0.f;
    for (int i = beg; i < end; ++i) {
        int s = ebuf[i];
        float e = __expf(lrelu2(asg[(size_t)s * 4 + h] + ad) - m);
        denom += e;
        const float4* hv = (const float4*)(hg + (size_t)s * 96 + h * 24);
#pragma unroll
        for (int q = 0; q < 6; ++q) {
            float4 v = hv[q];
            acc[q * 4 + 0] += e * v.x;
            acc[q * 4 + 1] += e * v.y;
            acc[q * 4 + 2] += e * v.z;
            acc[q * 4 + 3] += e * v.w;
        }
    }
    float scale = 0.25f / (denom + 1e-16f);
    float* g = gout + (size_t)n * 24;
#pragma unroll
    for (int c = 0; c < 24; ++c) {
        float v = acc[c] * scale;
        v += __shfl_xor(v, 1);
        v += __shfl_xor(v, 2);
        if ((c & 3) == h) {
            v += bias[c];
            g[c] = v > 0.f ? v : expm1f(v);
        }
    }
}

// ---------- 8. per-graph Conv1d(24->8, k=62) + leaky_relu ----------
__global__ __launch_bounds__(256) void conv_k(
    const float* __restrict__ gat, const float* __restrict__ w,
    const float* __restrict__ b, float* __restrict__ out) {
    __shared__ float it[24][192];
    __shared__ float wsh[OCH * 24 * KW];  // 11904 floats
    int g = blockIdx.x, tid = threadIdx.x;
    for (int i = tid; i < NPG * 24; i += 256) {
        int p = i / 24, c = i % 24;
        it[c][p] = gat[(size_t)g * (NPG * 24) + i];
    }
    if (tid < 24 * 6) {
        int c = tid / 6;
        it[c][186 + (tid % 6)] = 0.f;
    }
    for (int i = tid; i < OCH * 24 * KW; i += 256) wsh[i] = w[i];
    __syncthreads();

    int o = tid >> 5, tt = tid & 31;
    int t0 = tt * 4;
    float bias = b[o];
    float a0 = bias, a1 = bias, a2 = bias, a3 = bias;
    for (int i = 0; i < 24; ++i) {
        const float* wr = &wsh[(o * 24 + i) * KW];
        const float* ir = &it[i][t0];
        float v0 = ir[0], v1 = ir[1], v2 = ir[2];
#pragma unroll
        for (int k = 0; k < KW; ++k) {
            float v3 = ir[k + 3];
            float wv = wr[k];
            a0 += wv * v0;
            a1 += wv * v1;
            a2 += wv * v2;
            a3 += wv * v3;
            v0 = v1; v1 = v2; v2 = v3;
        }
    }
    a0 = a0 > 0.f ? a0 : 0.01f * a0;
    a1 = a1 > 0.f ? a1 : 0.01f * a1;
    a2 = a2 > 0.f ? a2 : 0.01f * a2;
    a3 = a3 > 0.f ? a3 : 0.01f * a3;
    size_t base = ((size_t)g * OCH + o) * TOUT + t0;
    if (t0 + 0 < TOUT) out[base + 0] = a0;
    if (t0 + 1 < TOUT) out[base + 1] = a1;
    if (t0 + 2 < TOUT) out[base + 2] = a2;
    if (t0 + 3 < TOUT) out[base + 3] = a3;
}

extern "C" void kernel_launch(void* const* d_in, const int* in_sizes, int n_in,
                              void* d_out, int out_size, void* d_ws, size_t ws_size,
                              hipStream_t stream) {
    const float* x        = (const float*)d_in[0];
    const int*   ei       = (const int*)d_in[1];
    const float* bn_gamma = (const float*)d_in[3];
    const float* bn_beta  = (const float*)d_in[4];
    const float* lin_w    = (const float*)d_in[5];
    const float* att_src  = (const float*)d_in[6];
    const float* att_dst  = (const float*)d_in[7];
    const float* gat_bias = (const float*)d_in[8];
    const float* conv_w   = (const float*)d_in[9];
    const float* conv_b   = (const float*)d_in[10];
    float* out = (float*)d_out;
    float* wsf = (float*)d_ws;
    int*   wsi = (int*)d_ws;

    const int N = N_NODES;
    const int E = in_sizes[1] / 2;
    const int total = E + N;
    const int tot4 = (total + 3) & ~3;

    // ws layout (4-byte units, all segments 16B-aligned):
    // [0..63]   stats: double sum[5]+sumsq[5] (=20 floats); scale/shift @20..29
    // deg       N ints           (zeroed)
    // rowptr    N+4 ints
    // cursor    N ints
    // psum      256 ints
    // ebuf      tot4 ints
    // asg,adg   N*4 floats each
    // hg        N*96 floats
    // gout      N*24 floats
    int* deg    = wsi + 64;
    int* rowptr = deg + N;
    int* cursor = rowptr + N + 4;
    int* psum   = cursor + N;
    int* ebuf   = psum + 256;
    float* asg  = (float*)(ebuf + tot4);
    float* adg  = asg + (size_t)N * 4;
    float* hg   = adg + (size_t)N * 4;
    float* gout = hg + (size_t)N * 96;

    // zero stats + deg in one contiguous memset
    hipMemsetAsync(d_ws, 0, (64 + (size_t)N) * 4, stream);

    bn_stats<<<256, 256, 0, stream>>>(x, (double*)wsf);
    bn_finalize<<<1, 64, 0, stream>>>((const double*)wsf, bn_gamma, bn_beta, wsf + 20);
    node_linear<<<N / 64, 256, 0, stream>>>(x, wsf + 20, lin_w, att_src, att_dst,
                                            hg, asg, adg);
    int eb = (total + 255) / 256;
    deg_count<<<eb, 256, 0, stream>>>(ei, E, total, deg);
    scan_partial<<<N / 1024, 256, 0, stream>>>(deg, psum);
    scan_small<<<1, 64, 0, stream>>>(psum, rowptr, N / 1024);
    scan_final<<<N / 1024, 256, 0, stream>>>(deg, psum, rowptr, cursor);
    fill_buckets<<<eb, 256, 0, stream>>>(ei, E, total, cursor, ebuf);
    gat_gather<<<(N * 4) / 256, 256, 0, stream>>>(rowptr, ebuf, asg, adg, hg,
                                                  gat_bias, gout);
    conv_k<<<N / NPG, 256, 0, stream>>>(gout, conv_w, conv_b, out);
}

// Round 3
// 809.139 us; speedup vs baseline: 21.6767x; 1.2240x over previous
//
#include <hip/hip_runtime.h>
#include <hip/hip_bf16.h>
#include <math.h>

#define N_NODES 190464
#define F_IN 5
#define HEADS 4
#define C_OUT 24
#define NPG 186
#define KW 62
#define OCH 8
#define TOUT 125

// ---------- helpers ----------
__device__ __forceinline__ float lrelu2(float v) { return v > 0.f ? v : 0.2f * v; }

// pack two fp32 -> bf16 pair (RNE), lo in low 16 bits
__device__ __forceinline__ unsigned bfpack(float lo, float hi) {
    unsigned a = __float_as_uint(lo), b = __float_as_uint(hi);
    a += 0x7fffu + ((a >> 16) & 1u);
    b += 0x7fffu + ((b >> 16) & 1u);
    return (a >> 16) | (b & 0xffff0000u);
}

__device__ __forceinline__ void acc8(float* acc, int base, uint4 v, float e) {
    acc[base + 0] += e * __uint_as_float(v.x << 16);
    acc[base + 1] += e * __uint_as_float(v.x & 0xffff0000u);
    acc[base + 2] += e * __uint_as_float(v.y << 16);
    acc[base + 3] += e * __uint_as_float(v.y & 0xffff0000u);
    acc[base + 4] += e * __uint_as_float(v.z << 16);
    acc[base + 5] += e * __uint_as_float(v.z & 0xffff0000u);
    acc[base + 6] += e * __uint_as_float(v.w << 16);
    acc[base + 7] += e * __uint_as_float(v.w & 0xffff0000u);
}

// ---------- 1. BN batch statistics ----------
__global__ __launch_bounds__(256) void bn_stats(const float* __restrict__ x,
                                                double* __restrict__ stats) {
    double s[5] = {0, 0, 0, 0, 0}, ss[5] = {0, 0, 0, 0, 0};
    int stride = gridDim.x * blockDim.x;
    for (int n = blockIdx.x * blockDim.x + threadIdx.x; n < N_NODES; n += stride) {
#pragma unroll
        for (int f = 0; f < 5; ++f) {
            float v = x[n * 5 + f];
            s[f] += v;
            ss[f] += (double)v * (double)v;
        }
    }
#pragma unroll
    for (int f = 0; f < 5; ++f) {
        for (int off = 32; off; off >>= 1) {
            s[f] += __shfl_down(s[f], off);
            ss[f] += __shfl_down(ss[f], off);
        }
    }
    if ((threadIdx.x & 63) == 0) {
#pragma unroll
        for (int f = 0; f < 5; ++f) {
            unsafeAtomicAdd(&stats[f], s[f]);
            unsafeAtomicAdd(&stats[5 + f], ss[f]);
        }
    }
}

// ---------- 2. finalize BN to scale/shift ----------
__global__ void bn_finalize(const double* __restrict__ stats,
                            const float* __restrict__ gamma,
                            const float* __restrict__ beta,
                            float* __restrict__ sc) {
    int f = threadIdx.x;
    if (f < 5) {
        double mu = stats[f] / (double)N_NODES;
        double var = stats[5 + f] / (double)N_NODES - mu * mu;
        double rstd = 1.0 / sqrt(var + 1e-5);
        float scale = (float)rstd * gamma[f];
        sc[f] = scale;
        sc[5 + f] = beta[f] - (float)mu * scale;
    }
}

// ---------- 3. per-node linear + attention coeffs; h written as bf16 ----------
__global__ __launch_bounds__(256) void node_linear(
    const float* __restrict__ x, const float* __restrict__ sc,
    const float* __restrict__ lin_w, const float* __restrict__ att_src,
    const float* __restrict__ att_dst, unsigned* __restrict__ hgb,
    float* __restrict__ asg, float* __restrict__ adg) {
    __shared__ float wsm[480];
    __shared__ float asv[96];
    __shared__ float adv[96];
    __shared__ float xt[320];
    __shared__ float scs[10];

    int tid = threadIdx.x;
    int n0 = blockIdx.x * 64;
    for (int i = tid; i < 480; i += 256) wsm[i] = lin_w[i];
    if (tid < 96) asv[tid] = att_src[tid];
    else if (tid < 192) adv[tid - 96] = att_dst[tid - 96];
    for (int i = tid; i < 320; i += 256) xt[i] = x[(size_t)n0 * 5 + i];
    if (tid < 10) scs[tid] = sc[tid];
    __syncthreads();

    int nl = tid >> 2, hh = tid & 3;
    float xn[5];
#pragma unroll
    for (int f = 0; f < 5; ++f) xn[f] = xt[nl * 5 + f] * scs[f] + scs[5 + f];
    float hv[24];
    float av = 0.f, bv = 0.f;
#pragma unroll
    for (int c = 0; c < 24; ++c) {
        int o = hh * 24 + c;
        float acc = 0.f;
#pragma unroll
        for (int f = 0; f < 5; ++f) acc += wsm[o * 5 + f] * xn[f];
        hv[c] = acc;
        av += acc * asv[o];
        bv += acc * adv[o];
    }
    asg[(size_t)n0 * 4 + tid] = av;
    adg[(size_t)n0 * 4 + tid] = bv;
    // pack 24 channels -> 12 uints -> 3 uint4 stores
    uint4* dst = (uint4*)(hgb + ((size_t)(n0 + nl) * 48 + hh * 12));
#pragma unroll
    for (int q = 0; q < 3; ++q) {
        uint4 u;
        u.x = bfpack(hv[q * 8 + 0], hv[q * 8 + 1]);
        u.y = bfpack(hv[q * 8 + 2], hv[q * 8 + 3]);
        u.z = bfpack(hv[q * 8 + 4], hv[q * 8 + 5]);
        u.w = bfpack(hv[q * 8 + 6], hv[q * 8 + 7]);
        dst[q] = u;
    }
}

// ---------- 4. degree count (by dst, incl. self loops) ----------
__global__ __launch_bounds__(256) void deg_count(
    const int* __restrict__ ei, const int E, const int total,
    int* __restrict__ deg) {
    int idx = blockIdx.x * 256 + threadIdx.x;
    if (idx >= total) return;
    int dst = (idx < E) ? ei[E + idx] : (idx - E);
    atomicAdd(&deg[dst], 1);
}

// ---------- 5a. per-block partial sums (1024 elems/block, 186 blocks) ----------
__global__ __launch_bounds__(256) void scan_partial(const int* __restrict__ deg,
                                                    int* __restrict__ psum) {
    __shared__ int red[4];
    int b = blockIdx.x, tid = threadIdx.x;
    int s = 0;
    for (int i = tid; i < 1024; i += 256) s += deg[b * 1024 + i];
    for (int off = 32; off; off >>= 1) s += __shfl_down(s, off);
    if ((tid & 63) == 0) red[tid >> 6] = s;
    __syncthreads();
    if (tid == 0) psum[b] = red[0] + red[1] + red[2] + red[3];
}

// ---------- 5b. parallel exclusive scan of 186 block sums (1 block) ----------
__global__ __launch_bounds__(256) void scan_small(int* __restrict__ psum,
                                                  int* __restrict__ rowptr,
                                                  const int nblk) {
    __shared__ int ts[256];
    int tid = threadIdx.x;
    int v = (tid < nblk) ? psum[tid] : 0;
    ts[tid] = v;
    __syncthreads();
    for (int off = 1; off < 256; off <<= 1) {
        int u = (tid >= off) ? ts[tid - off] : 0;
        __syncthreads();
        ts[tid] += u;
        __syncthreads();
    }
    if (tid < nblk) psum[tid] = ts[tid] - v;
    if (tid == nblk - 1) rowptr[N_NODES] = ts[tid];
}

// ---------- 5c. block exclusive scan + write rowptr & cursor ----------
__global__ __launch_bounds__(256) void scan_final(
    const int* __restrict__ deg, const int* __restrict__ psum,
    int* __restrict__ rowptr, int* __restrict__ cursor) {
    __shared__ int ts[256];
    int b = blockIdx.x, tid = threadIdx.x;
    int base = b * 1024 + tid * 4;
    int d0 = deg[base], d1 = deg[base + 1], d2 = deg[base + 2], d3 = deg[base + 3];
    int tsum = d0 + d1 + d2 + d3;
    ts[tid] = tsum;
    __syncthreads();
    for (int off = 1; off < 256; off <<= 1) {
        int v = (tid >= off) ? ts[tid - off] : 0;
        __syncthreads();
        ts[tid] += v;
        __syncthreads();
    }
    int excl = ts[tid] - tsum + psum[b];
    int r0 = excl, r1 = r0 + d0, r2 = r1 + d1, r3 = r2 + d2;
    rowptr[base] = r0; rowptr[base + 1] = r1;
    rowptr[base + 2] = r2; rowptr[base + 3] = r3;
    cursor[base] = r0; cursor[base + 1] = r1;
    cursor[base + 2] = r2; cursor[base + 3] = r3;
}

// ---------- 6. fill edge buckets ----------
__global__ __launch_bounds__(256) void fill_buckets(
    const int* __restrict__ ei, const int E, const int total,
    int* __restrict__ cursor, int* __restrict__ ebuf) {
    int idx = blockIdx.x * 256 + threadIdx.x;
    if (idx >= total) return;
    int src, dst;
    if (idx < E) { src = ei[idx]; dst = ei[E + idx]; }
    else { src = dst = idx - E; }
    int pos = atomicAdd(&cursor[dst], 1);
    ebuf[pos] = src;
}

// ---------- 7. gather GAT: single-pass softmax + weighted sum + ELU ----------
__global__ __launch_bounds__(256) void gat_gather(
    const int* __restrict__ rowptr, const int* __restrict__ ebuf,
    const float* __restrict__ asg, const float* __restrict__ adg,
    const unsigned* __restrict__ hgb, const float* __restrict__ bias,
    float* __restrict__ gout) {
    int t = blockIdx.x * 256 + threadIdx.x;
    int n = t >> 2, h = t & 3;
    if (n >= N_NODES) return;
    int beg = rowptr[n], end = rowptr[n + 1];
    float ad = adg[(size_t)n * 4 + h];
    float acc[24];
#pragma unroll
    for (int c = 0; c < 24; ++c) acc[c] = 0.f;
    float denom = 0.f;
    int i = beg;
    for (; i + 1 < end; i += 2) {
        int s0 = ebuf[i], s1 = ebuf[i + 1];
        float a0 = asg[(size_t)s0 * 4 + h];
        float a1 = asg[(size_t)s1 * 4 + h];
        const uint4* p0 = (const uint4*)(hgb + ((size_t)s0 * 48 + h * 12));
        const uint4* p1 = (const uint4*)(hgb + ((size_t)s1 * 48 + h * 12));
        uint4 A0 = p0[0], B0 = p0[1], C0 = p0[2];
        uint4 A1 = p1[0], B1 = p1[1], C1 = p1[2];
        float e0 = __expf(lrelu2(a0 + ad));
        float e1 = __expf(lrelu2(a1 + ad));
        denom += e0 + e1;
        acc8(acc, 0, A0, e0); acc8(acc, 8, B0, e0); acc8(acc, 16, C0, e0);
        acc8(acc, 0, A1, e1); acc8(acc, 8, B1, e1); acc8(acc, 16, C1, e1);
    }
    if (i < end) {
        int s0 = ebuf[i];
        float a0 = asg[(size_t)s0 * 4 + h];
        const uint4* p0 = (const uint4*)(hgb + ((size_t)s0 * 48 + h * 12));
        uint4 A0 = p0[0], B0 = p0[1], C0 = p0[2];
        float e0 = __expf(lrelu2(a0 + ad));
        denom += e0;
        acc8(acc, 0, A0, e0); acc8(acc, 8, B0, e0); acc8(acc, 16, C0, e0);
    }
    float scale = 0.25f / (denom + 1e-16f);
    float* g = gout + (size_t)n * 24;
#pragma unroll
    for (int c = 0; c < 24; ++c) {
        float v = acc[c] * scale;
        v += __shfl_xor(v, 1);
        v += __shfl_xor(v, 2);
        if ((c & 3) == h) {
            v += bias[c];
            g[c] = v > 0.f ? v : expm1f(v);
        }
    }
}

// ---------- 8. per-graph Conv1d(24->8, k=62) + leaky_relu ----------
__global__ __launch_bounds__(256) void conv_k(
    const float* __restrict__ gat, const float* __restrict__ w,
    const float* __restrict__ b, float* __restrict__ out) {
    __shared__ float it[24][192];
    __shared__ float wsh[OCH * 24 * KW];  // 11904 floats
    int g = blockIdx.x, tid = threadIdx.x;
    for (int i = tid; i < NPG * 24; i += 256) {
        int p = i / 24, c = i % 24;
        it[c][p] = gat[(size_t)g * (NPG * 24) + i];
    }
    if (tid < 24 * 6) {
        int c = tid / 6;
        it[c][186 + (tid % 6)] = 0.f;
    }
    for (int i = tid; i < OCH * 24 * KW; i += 256) wsh[i] = w[i];
    __syncthreads();

    int o = tid >> 5, tt = tid & 31;
    int t0 = tt * 4;
    float bias = b[o];
    float a0 = bias, a1 = bias, a2 = bias, a3 = bias;
    for (int i = 0; i < 24; ++i) {
        const float* wr = &wsh[(o * 24 + i) * KW];
        const float* ir = &it[i][t0];
        float v0 = ir[0], v1 = ir[1], v2 = ir[2];
#pragma unroll
        for (int k = 0; k < KW; ++k) {
            float v3 = ir[k + 3];
            float wv = wr[k];
            a0 += wv * v0;
            a1 += wv * v1;
            a2 += wv * v2;
            a3 += wv * v3;
            v0 = v1; v1 = v2; v2 = v3;
        }
    }
    a0 = a0 > 0.f ? a0 : 0.01f * a0;
    a1 = a1 > 0.f ? a1 : 0.01f * a1;
    a2 = a2 > 0.f ? a2 : 0.01f * a2;
    a3 = a3 > 0.f ? a3 : 0.01f * a3;
    size_t base = ((size_t)g * OCH + o) * TOUT + t0;
    if (t0 + 0 < TOUT) out[base + 0] = a0;
    if (t0 + 1 < TOUT) out[base + 1] = a1;
    if (t0 + 2 < TOUT) out[base + 2] = a2;
    if (t0 + 3 < TOUT) out[base + 3] = a3;
}

extern "C" void kernel_launch(void* const* d_in, const int* in_sizes, int n_in,
                              void* d_out, int out_size, void* d_ws, size_t ws_size,
                              hipStream_t stream) {
    const float* x        = (const float*)d_in[0];
    const int*   ei       = (const int*)d_in[1];
    const float* bn_gamma = (const float*)d_in[3];
    const float* bn_beta  = (const float*)d_in[4];
    const float* lin_w    = (const float*)d_in[5];
    const float* att_src  = (const float*)d_in[6];
    const float* att_dst  = (const float*)d_in[7];
    const float* gat_bias = (const float*)d_in[8];
    const float* conv_w   = (const float*)d_in[9];
    const float* conv_b   = (const float*)d_in[10];
    float* out = (float*)d_out;
    float* wsf = (float*)d_ws;
    int*   wsi = (int*)d_ws;

    const int N = N_NODES;
    const int E = in_sizes[1] / 2;
    const int total = E + N;
    const int tot4 = (total + 3) & ~3;

    // ws layout (4-byte units, all segments 16B-aligned):
    // [0..63]   stats: double sum[5]+sumsq[5] (=20 floats); scale/shift @20..29
    // deg       N ints           (zeroed)
    // rowptr    N+4 ints
    // cursor    N ints
    // psum      256 ints
    // ebuf      tot4 ints
    // asg,adg   N*4 floats each
    // hgb       N*48 uints (bf16 h)
    // gout      N*24 floats
    int* deg    = wsi + 64;
    int* rowptr = deg + N;
    int* cursor = rowptr + N + 4;
    int* psum   = cursor + N;
    int* ebuf   = psum + 256;
    float* asg  = (float*)(ebuf + tot4);
    float* adg  = asg + (size_t)N * 4;
    unsigned* hgb = (unsigned*)(adg + (size_t)N * 4);
    float* gout = (float*)(hgb + (size_t)N * 48);

    // zero stats + deg in one contiguous memset
    hipMemsetAsync(d_ws, 0, (64 + (size_t)N) * 4, stream);

    bn_stats<<<256, 256, 0, stream>>>(x, (double*)wsf);
    bn_finalize<<<1, 64, 0, stream>>>((const double*)wsf, bn_gamma, bn_beta, wsf + 20);
    node_linear<<<N / 64, 256, 0, stream>>>(x, wsf + 20, lin_w, att_src, att_dst,
                                            hgb, asg, adg);
    int eb = (total + 255) / 256;
    deg_count<<<eb, 256, 0, stream>>>(ei, E, total, deg);
    scan_partial<<<N / 1024, 256, 0, stream>>>(deg, psum);
    scan_small<<<1, 256, 0, stream>>>(psum, rowptr, N / 1024);
    scan_final<<<N / 1024, 256, 0, stream>>>(deg, psum, rowptr, cursor);
    fill_buckets<<<eb, 256, 0, stream>>>(ei, E, total, cursor, ebuf);
    gat_gather<<<(N * 4) / 256, 256, 0, stream>>>(rowptr, ebuf, asg, adg, hgb,
                                                  gat_bias, gout);
    conv_k<<<N / NPG, 256, 0, stream>>>(gout, conv_w, conv_b, out);
}